// Round 21
// baseline (119.307 us; speedup 1.0000x reference)
//
#include <hip/hip_runtime.h>
#include <hip/hip_bf16.h>

// Nav_64939905516231 (VIN value iteration), MI355X gfx950.
// B=64,H=W=64,dim_h=150,n_hat=8,n_act=4,K=10. fp32 in/out, maze int32.
// Collapses: r = conv5x5(m,W_eff)+b_eff (150ch folded); q_t = q0 + conv5x5(v,w).
// R21 = R20 resubmitted (R20 hit GPUAcquisitionTimeout, never measured):
// vi with ONE barrier per step: half-maxes live in double-buffered
// tbuf[2][56][2][68]; taps read BOTH halves + on-the-fly max (4 b128 + 8 vmax
// per tap row). Phase-B combine pass and its barrier deleted (21 -> 13
// syncs). rq unchanged from R19 (parallel prep + r + q0 contiguous layout).
// Facts bank: 1024-thr => VGPR64 (GB spills); 512-thr => VGPR<=128; occupancy
// pinned 2 waves/SIMD by unified VGPR+AGPR (~88+100) budget; grid
// oversubscription serializes; ~44us fills are harness; fusion (R18) loses.

#define NHAT 8
#define DIMH 150

typedef float v2f __attribute__((ext_vector_type(2)));

// ------- rq: prep (parallel) + r = table-conv(maze) + q0 -------
// q0 layout: q0g[((b*64+gy)*2 + half)*64 + gx] as float4 (4 ch of that half).
__global__ __launch_bounds__(512) void rq_kernel(
    const int* __restrict__ maze, const float* __restrict__ emb,
    const float* __restrict__ encode_w, const float* __restrict__ encode_b,
    const float* __restrict__ r_w, const float* __restrict__ q_w,
    float* __restrict__ q0g) {
  __shared__ float wpart[5][50];
  __shared__ float bpart[152];
  __shared__ float weff[2][25];
  __shared__ float Ts[4][25];
  __shared__ float bsh;
  __shared__ v2f qw2[25][4];
  __shared__ unsigned char mzt[24][68];
  __shared__ float rt[20][68];

  int tid = threadIdx.x;
  int b = blockIdx.y, A0 = blockIdx.x * 16;

  if (tid < 100) {
    int k = tid >> 2, j = tid & 3;
    qw2[k][j] = (v2f){q_w[(2 * j) * 25 + k], q_w[(2 * j + 1) * 25 + k]};
  }
  if (tid >= 256 && tid < 506) {
    int t2 = tid - 256;
    int chunk = t2 / 50, ik = t2 % 50;
    int i = ik / 25, k = ik % 25;
    int c0 = chunk * 30;
    float s = 0.f;
    for (int c = c0; c < c0 + 30; ++c)
      s += r_w[c] * encode_w[c * 50 + i * 25 + k];
    wpart[chunk][ik] = s;
  }
  if (tid >= 100 && tid < 250) {
    int c = tid - 100;
    bpart[c] = r_w[c] * encode_b[c];
  }
  for (int i = tid; i < 24 * 68; i += 512) {
    int mr = i / 68, mc = i % 68;
    int gy = A0 - 4 + mr, gx = mc - 2;
    unsigned char v = 3;
    if (gy >= 0 && gy < 64 && gx >= 0 && gx < 64)
      v = (unsigned char)maze[(b * 64 + gy) * 64 + gx];
    mzt[mr][mc] = v;
  }
  __syncthreads();
  if (tid < 50) {
    float s = 0.f;
#pragma unroll
    for (int ch = 0; ch < 5; ++ch) s += wpart[ch][tid];
    weff[tid / 25][tid % 25] = s;
  }
  if (tid == 50) {
    float s = 0.f;
    for (int c = 0; c < 150; ++c) s += bpart[c];
    bsh = s;
  }
  __syncthreads();
  if (tid < 100) {
    int val = tid / 25, k = tid % 25;
    float t = 0.f;
    if (val < 3) t = weff[0][k] * emb[val * 2] + weff[1][k] * emb[val * 2 + 1];
    Ts[val][k] = t;  // row 3 == 0 (padding sentinel)
  }
  __syncthreads();
  for (int i = tid; i < 20 * 68; i += 512) {
    int rr = i / 68, cc = i % 68;
    int gy = A0 - 2 + rr, gx = cc - 2;
    float v = 0.f;
    if (gy >= 0 && gy < 64 && gx >= 0 && gx < 64) {
      v = bsh;
#pragma unroll
      for (int ky = 0; ky < 5; ++ky)
#pragma unroll
        for (int kx = 0; kx < 5; ++kx)
          v += Ts[mzt[rr + ky][cc - 2 + kx]][ky * 5 + kx];
    }
    rt[rr][cc] = v;
  }
  __syncthreads();
  for (int i = tid; i < 16 * 64; i += 512) {
    int ly = i >> 6, gx = i & 63;
    int gy = A0 + ly;
    v2f acc[4];
#pragma unroll
    for (int j = 0; j < 4; ++j) acc[j] = (v2f){0.f, 0.f};
#pragma unroll
    for (int ky = 0; ky < 5; ++ky)
#pragma unroll
      for (int kx = 0; kx < 5; ++kx) {
        int k = ky * 5 + kx;
        float vv = rt[ly + ky][gx + kx];
        v2f vv2 = (v2f){vv, vv};
#pragma unroll
        for (int j = 0; j < 4; ++j) acc[j] += qw2[k][j] * vv2;
      }
    size_t base = ((size_t)(b * 64 + gy) * 2) * 64 + gx;
    *(float4*)&q0g[(base)*4] = make_float4(acc[0].x, acc[0].y, acc[1].x, acc[1].y);
    *(float4*)&q0g[(base + 64) * 4] =
        make_float4(acc[2].x, acc[2].y, acc[3].x, acc[3].y);
  }
}

// =============== vi: 10 fused VI steps + projection, 1 barrier/step =========
// Block (512 thr = 8 waves) owns rows [a0, a0+16); grid 256 (1 blk/CU).
// Wave = (slot = wave>>1, half = wave&1); lane = (roff = lane>>4,
// i4 = 4*(lane&15)). State: tbuf[buf][lr][half][col], lr = r - a0 + 20 in
// [0,56), col = px + 2. Taps: per tap row read both halves (4 b128) + 8 vmax.
// Off-image rows/cols are never written -> zero-init = conv zero-padding.
__global__ __launch_bounds__(512, 2) void vi_kernel(
    const float* __restrict__ q0g, const float* __restrict__ w,
    const float* __restrict__ fc_w, float* __restrict__ out) {
  __shared__ __align__(16) float tbuf[2][56][2][68];  // 59.5 KB
  __shared__ v2f wl2[25][4];

  int tid = threadIdx.x;
  int b = blockIdx.y, a0 = blockIdx.x * 16;
  int wave = tid >> 6, lane = tid & 63;
  int half = wave & 1, slot = wave >> 1;
  int roff = lane >> 4, i4 = (lane & 15) * 4;

  if (tid < 100) {
    int k = tid >> 2, j = tid & 3;
    wl2[k][j] = (v2f){w[(2 * j) * 25 + k], w[(2 * j + 1) * 25 + k]};
  }
  for (int i = tid; i < 2 * 56 * 2 * 68; i += 512) ((float*)tbuf)[i] = 0.f;
  __syncthreads();

  // this wave's 4 channels -> 50 v2f = 100 floats (regs/AGPRs, no spill)
  v2f wr0[25], wr1[25];
#pragma unroll
  for (int k = 0; k < 25; ++k) {
    wr0[k] = wl2[k][2 * half];
    wr1[k] = wl2[k][2 * half + 1];
  }

  const float* q0b = q0g + (size_t)b * 64 * 2 * 64 * 4;
  int cur = 0;

  // v0 = max_c q0 on [a0-20, a0+36): write same value to both halves
  {
    int s = max(0, a0 - 20), e = min(64, a0 + 36);
    int gx = lane;
    for (int r = s + wave; r < e; r += 8) {
      float4 f0 = *(const float4*)&q0b[(((size_t)r * 2 + 0) * 64 + gx) * 4];
      float4 f1 = *(const float4*)&q0b[(((size_t)r * 2 + 1) * 64 + gx) * 4];
      float m = fmaxf(fmaxf(fmaxf(f0.x, f0.y), fmaxf(f0.z, f0.w)),
                      fmaxf(fmaxf(f1.x, f1.y), fmaxf(f1.z, f1.w)));
      int lr = r - a0 + 20;
      tbuf[0][lr][0][gx + 2] = m;
      tbuf[0][lr][1][gx + 2] = m;
    }
  }
  __syncthreads();

  for (int t = 1; t <= 9; ++t) {
    int hh = 2 * (10 - t);
    int s = max(0, a0 - hh), e = min(64, a0 + 16 + hh);
    for (int rb = s + 4 * slot; rb < e; rb += 16) {
      int r = rb + roff;
      if (r < e) {
        int lr = r - a0 + 20;
        const float4* qp =
            (const float4*)&q0b[(((size_t)r * 2 + half) * 64 + i4) * 4];
        float4 qv0 = qp[0], qv1 = qp[1], qv2 = qp[2], qv3 = qp[3];
        v2f aA[4], aB[4];
        aA[0] = (v2f){qv0.x, qv0.y}; aB[0] = (v2f){qv0.z, qv0.w};
        aA[1] = (v2f){qv1.x, qv1.y}; aB[1] = (v2f){qv1.z, qv1.w};
        aA[2] = (v2f){qv2.x, qv2.y}; aB[2] = (v2f){qv2.z, qv2.w};
        aA[3] = (v2f){qv3.x, qv3.y}; aB[3] = (v2f){qv3.z, qv3.w};
#pragma unroll
        for (int jj = 0; jj < 5; ++jj) {
          const float* r0p = &tbuf[cur][lr - 2 + jj][0][i4];
          const float* r1p = &tbuf[cur][lr - 2 + jj][1][i4];
          float4 ha = *(const float4*)r0p;
          float4 hb = *(const float4*)(r0p + 4);
          float4 ka = *(const float4*)r1p;
          float4 kb = *(const float4*)(r1p + 4);
          float f[8] = {fmaxf(ha.x, ka.x), fmaxf(ha.y, ka.y),
                        fmaxf(ha.z, ka.z), fmaxf(ha.w, ka.w),
                        fmaxf(hb.x, kb.x), fmaxf(hb.y, kb.y),
                        fmaxf(hb.z, kb.z), fmaxf(hb.w, kb.w)};
#pragma unroll
          for (int kx = 0; kx < 5; ++kx) {
            int k = jj * 5 + kx;
            v2f w0 = wr0[k], w1 = wr1[k];
#pragma unroll
            for (int j = 0; j < 4; ++j) {
              v2f vv2 = (v2f){f[j + kx], f[j + kx]};
              aA[j] += w0 * vv2;
              aB[j] += w1 * vv2;
            }
          }
        }
        float m0 = fmaxf(fmaxf(aA[0].x, aA[0].y), fmaxf(aB[0].x, aB[0].y));
        float m1 = fmaxf(fmaxf(aA[1].x, aA[1].y), fmaxf(aB[1].x, aB[1].y));
        float m2 = fmaxf(fmaxf(aA[2].x, aA[2].y), fmaxf(aB[2].x, aB[2].y));
        float m3 = fmaxf(fmaxf(aA[3].x, aA[3].y), fmaxf(aB[3].x, aB[3].y));
        float* dst = &tbuf[cur ^ 1][lr][half][i4 + 2];
        dst[0] = m0; dst[1] = m1; dst[2] = m2; dst[3] = m3;
      }
    }
    __syncthreads();
    cur ^= 1;
  }

  // final step t=10 + projection: rows [a0, a0+16)
  float fcp[4][4];
#pragma unroll
  for (int a = 0; a < 4; ++a)
#pragma unroll
    for (int cc = 0; cc < 4; ++cc) fcp[a][cc] = fc_w[a * 8 + 4 * half + cc];
  float* ptmp = (float*)&tbuf[cur ^ 1][0][0][0];  // dead buffer, 16 KB reuse

  {
    int r = a0 + 4 * slot + roff;  // in [a0, a0+16)
    int lr = r - a0 + 20;
    const float4* qp =
        (const float4*)&q0b[(((size_t)r * 2 + half) * 64 + i4) * 4];
    float4 qv0 = qp[0], qv1 = qp[1], qv2 = qp[2], qv3 = qp[3];
    v2f aA[4], aB[4];
    aA[0] = (v2f){qv0.x, qv0.y}; aB[0] = (v2f){qv0.z, qv0.w};
    aA[1] = (v2f){qv1.x, qv1.y}; aB[1] = (v2f){qv1.z, qv1.w};
    aA[2] = (v2f){qv2.x, qv2.y}; aB[2] = (v2f){qv2.z, qv2.w};
    aA[3] = (v2f){qv3.x, qv3.y}; aB[3] = (v2f){qv3.z, qv3.w};
#pragma unroll
    for (int jj = 0; jj < 5; ++jj) {
      const float* r0p = &tbuf[cur][lr - 2 + jj][0][i4];
      const float* r1p = &tbuf[cur][lr - 2 + jj][1][i4];
      float4 ha = *(const float4*)r0p;
      float4 hb = *(const float4*)(r0p + 4);
      float4 ka = *(const float4*)r1p;
      float4 kb = *(const float4*)(r1p + 4);
      float f[8] = {fmaxf(ha.x, ka.x), fmaxf(ha.y, ka.y),
                    fmaxf(ha.z, ka.z), fmaxf(ha.w, ka.w),
                    fmaxf(hb.x, kb.x), fmaxf(hb.y, kb.y),
                    fmaxf(hb.z, kb.z), fmaxf(hb.w, kb.w)};
#pragma unroll
      for (int kx = 0; kx < 5; ++kx) {
        int k = jj * 5 + kx;
        v2f w0 = wr0[k], w1 = wr1[k];
#pragma unroll
        for (int j = 0; j < 4; ++j) {
          v2f vv2 = (v2f){f[j + kx], f[j + kx]};
          aA[j] += w0 * vv2;
          aB[j] += w1 * vv2;
        }
      }
    }
    float4 pp[4];
#pragma unroll
    for (int j = 0; j < 4; ++j) {
      float q0v = aA[j].x, q1v = aA[j].y, q2v = aB[j].x, q3v = aB[j].y;
      pp[j].x = fcp[0][0] * q0v + fcp[0][1] * q1v + fcp[0][2] * q2v + fcp[0][3] * q3v;
      pp[j].y = fcp[1][0] * q0v + fcp[1][1] * q1v + fcp[1][2] * q2v + fcp[1][3] * q3v;
      pp[j].z = fcp[2][0] * q0v + fcp[2][1] * q1v + fcp[2][2] * q2v + fcp[2][3] * q3v;
      pp[j].w = fcp[3][0] * q0v + fcp[3][1] * q1v + fcp[3][2] * q2v + fcp[3][3] * q3v;
    }
    __syncthreads();  // tbuf[cur^1] fully dead before reuse
    if (half == 1) {
#pragma unroll
      for (int j = 0; j < 4; ++j)
        *(float4*)&ptmp[(((r - a0) * 64) + i4 + j) * 4] = pp[j];
    }
    __syncthreads();
    if (half == 0) {
#pragma unroll
      for (int j = 0; j < 4; ++j) {
        float4 o = *(const float4*)&ptmp[(((r - a0) * 64) + i4 + j) * 4];
        o.x += pp[j].x; o.y += pp[j].y; o.z += pp[j].z; o.w += pp[j].w;
        *(float4*)&out[((size_t)((b * 64 + r) * 64 + i4 + j)) * 4] = o;
      }
    }
  }
}

extern "C" void kernel_launch(void* const* d_in, const int* in_sizes, int n_in,
                              void* d_out, int out_size, void* d_ws, size_t ws_size,
                              hipStream_t stream) {
  const int* maze = (const int*)d_in[0];
  const float* emb = (const float*)d_in[1];
  const float* encode_w = (const float*)d_in[2];
  const float* encode_b = (const float*)d_in[3];
  const float* r_w = (const float*)d_in[4];
  const float* q_w = (const float*)d_in[5];
  const float* w = (const float*)d_in[6];
  const float* fc_w = (const float*)d_in[7];
  float* out = (float*)d_out;

  float* q0g = (float*)d_ws;  // 64*64*2*64*4 floats = 8 MB

  rq_kernel<<<dim3(4, 64), 512, 0, stream>>>(maze, emb, encode_w, encode_b,
                                             r_w, q_w, q0g);
  vi_kernel<<<dim3(4, 64), 512, 0, stream>>>(q0g, w, fc_w, out);
}

// Round 22
// 113.833 us; speedup vs baseline: 1.0481x; 1.0481x over previous
//
#include <hip/hip_runtime.h>
#include <hip/hip_bf16.h>

// Nav_64939905516231 (VIN value iteration), MI355X gfx950.
// B=64,H=W=64,dim_h=150,n_hat=8,n_act=4,K=10. fp32 in/out, maze int32.
// Collapses: r = conv5x5(m,W_eff)+b_eff (150ch folded); q_t = q0 + conv5x5(v,w).
// R22 = R19 restored (measured best: 115.2us total). R21's 1-barrier variant
// regressed (2x tap reads, 4M bank conflicts). vi plateau ~43-48us across 8
// structural variants: LDS-latency-chain bound at the hard 2-waves/SIMD pin
// (unified VGPR+AGPR budget ~88+100 per wave). ~44us ws-poison fill and
// ~18us dispatch overhead are harness-fixed.
// rq = parallel prep (chunked W_eff reduce) + r + q0 in [b][row][half][px][4]
// layout (vi reads 4 contiguous float4s). vi = channel-split wave halves,
// 4px/lane b128 taps, tmp combine, 2 barriers/step.

#define NHAT 8
#define DIMH 150

typedef float v2f __attribute__((ext_vector_type(2)));

// ------- rq: prep (parallel) + r = table-conv(maze) + q0 -------
// q0 layout: q0g[((b*64+gy)*2 + half)*64 + gx] as float4 (4 ch of that half).
__global__ __launch_bounds__(512) void rq_kernel(
    const int* __restrict__ maze, const float* __restrict__ emb,
    const float* __restrict__ encode_w, const float* __restrict__ encode_b,
    const float* __restrict__ r_w, const float* __restrict__ q_w,
    float* __restrict__ q0g) {
  __shared__ float wpart[5][50];
  __shared__ float bpart[152];
  __shared__ float weff[2][25];
  __shared__ float Ts[4][25];
  __shared__ float bsh;
  __shared__ v2f qw2[25][4];
  __shared__ unsigned char mzt[24][68];
  __shared__ float rt[20][68];

  int tid = threadIdx.x;
  int b = blockIdx.y, A0 = blockIdx.x * 16;

  // P0: weight stage + W_eff partials + maze tile
  if (tid < 100) {
    int k = tid >> 2, j = tid & 3;
    qw2[k][j] = (v2f){q_w[(2 * j) * 25 + k], q_w[(2 * j + 1) * 25 + k]};
  }
  if (tid >= 256 && tid < 506) {
    int t2 = tid - 256;
    int chunk = t2 / 50, ik = t2 % 50;
    int i = ik / 25, k = ik % 25;
    int c0 = chunk * 30;
    float s = 0.f;
    for (int c = c0; c < c0 + 30; ++c)
      s += r_w[c] * encode_w[c * 50 + i * 25 + k];
    wpart[chunk][ik] = s;
  }
  if (tid >= 100 && tid < 250) {
    int c = tid - 100;
    bpart[c] = r_w[c] * encode_b[c];
  }
  for (int i = tid; i < 24 * 68; i += 512) {
    int mr = i / 68, mc = i % 68;
    int gy = A0 - 4 + mr, gx = mc - 2;
    unsigned char v = 3;
    if (gy >= 0 && gy < 64 && gx >= 0 && gx < 64)
      v = (unsigned char)maze[(b * 64 + gy) * 64 + gx];
    mzt[mr][mc] = v;
  }
  __syncthreads();
  // P1: reduce
  if (tid < 50) {
    float s = 0.f;
#pragma unroll
    for (int ch = 0; ch < 5; ++ch) s += wpart[ch][tid];
    weff[tid / 25][tid % 25] = s;
  }
  if (tid == 50) {
    float s = 0.f;
    for (int c = 0; c < 150; ++c) s += bpart[c];
    bsh = s;
  }
  __syncthreads();
  // P2: T table
  if (tid < 100) {
    int val = tid / 25, k = tid % 25;
    float t = 0.f;
    if (val < 3) t = weff[0][k] * emb[val * 2] + weff[1][k] * emb[val * 2 + 1];
    Ts[val][k] = t;  // row 3 == 0 (padding sentinel)
  }
  __syncthreads();
  // P3: r tile rows [A0-2, A0+18): r(A0-2+rr, cc-2) taps mzt[rr+ky][cc-2+kx]
  for (int i = tid; i < 20 * 68; i += 512) {
    int rr = i / 68, cc = i % 68;
    int gy = A0 - 2 + rr, gx = cc - 2;
    float v = 0.f;
    if (gy >= 0 && gy < 64 && gx >= 0 && gx < 64) {
      v = bsh;
#pragma unroll
      for (int ky = 0; ky < 5; ++ky)
#pragma unroll
        for (int kx = 0; kx < 5; ++kx)
          v += Ts[mzt[rr + ky][cc - 2 + kx]][ky * 5 + kx];
    }
    rt[rr][cc] = v;
  }
  __syncthreads();
  // P4: q0 on owned 16 rows -> [b][gy][half][gx] float4
  for (int i = tid; i < 16 * 64; i += 512) {
    int ly = i >> 6, gx = i & 63;
    int gy = A0 + ly;
    v2f acc[4];
#pragma unroll
    for (int j = 0; j < 4; ++j) acc[j] = (v2f){0.f, 0.f};
#pragma unroll
    for (int ky = 0; ky < 5; ++ky)
#pragma unroll
      for (int kx = 0; kx < 5; ++kx) {
        int k = ky * 5 + kx;
        float vv = rt[ly + ky][gx + kx];
        v2f vv2 = (v2f){vv, vv};
#pragma unroll
        for (int j = 0; j < 4; ++j) acc[j] += qw2[k][j] * vv2;
      }
    size_t base = ((size_t)(b * 64 + gy) * 2) * 64 + gx;
    *(float4*)&q0g[(base)*4] = make_float4(acc[0].x, acc[0].y, acc[1].x, acc[1].y);
    *(float4*)&q0g[(base + 64) * 4] =
        make_float4(acc[2].x, acc[2].y, acc[3].x, acc[3].y);
  }
}

// =============== vi: 10 fused VI steps + projection =================
// Block (512 thr = 8 waves) owns rows [a0, a0+16); grid 256 (1 blk/CU).
// Wave = (slot = wave>>1, half = wave&1); lane = (roff = lane>>4,
// i4 = 4*(lane&15)). Phase A: lane computes 4 px of row rb+roff for its 4
// channels; taps = 2 ds_read_b128 per tap row; q0 = 4 contiguous float4s.
// Half-maxes -> tmp; phase B combines -> vbuf[cur^1]. lr = r - a0 + 22.
__global__ __launch_bounds__(512, 2) void vi_kernel(
    const float* __restrict__ q0g, const float* __restrict__ w,
    const float* __restrict__ fc_w, float* __restrict__ out) {
  __shared__ __align__(16) float vbuf[2][60][68];  // 32.6 KB
  __shared__ __align__(16) float tmp[52][2][64];   // 26.6 KB (reused in proj)
  __shared__ v2f wl2[25][4];

  int tid = threadIdx.x;
  int b = blockIdx.y, a0 = blockIdx.x * 16;
  int wave = tid >> 6, lane = tid & 63;
  int half = wave & 1, slot = wave >> 1;
  int roff = lane >> 4, i4 = (lane & 15) * 4;

  if (tid < 100) {
    int k = tid >> 2, j = tid & 3;
    wl2[k][j] = (v2f){w[(2 * j) * 25 + k], w[(2 * j + 1) * 25 + k]};
  }
  for (int i = tid; i < 2 * 60 * 68; i += 512) ((float*)vbuf)[i] = 0.f;
  __syncthreads();

  // this wave's 4 channels -> 50 v2f = 100 floats (regs/AGPRs, no spill)
  v2f wr0[25], wr1[25];
#pragma unroll
  for (int k = 0; k < 25; ++k) {
    wr0[k] = wl2[k][2 * half];
    wr1[k] = wl2[k][2 * half + 1];
  }

  const float* q0b = q0g + (size_t)b * 64 * 2 * 64 * 4;
  int cur = 0;

  // v0 = max_c q0 on [a0-20, a0+36): full 8ch per lane, waves stride 8 rows
  {
    int s = max(0, a0 - 20), e = min(64, a0 + 36);
    int gx = lane;
    for (int r = s + wave; r < e; r += 8) {
      float4 f0 = *(const float4*)&q0b[(((size_t)r * 2 + 0) * 64 + gx) * 4];
      float4 f1 = *(const float4*)&q0b[(((size_t)r * 2 + 1) * 64 + gx) * 4];
      float m = fmaxf(fmaxf(fmaxf(f0.x, f0.y), fmaxf(f0.z, f0.w)),
                      fmaxf(fmaxf(f1.x, f1.y), fmaxf(f1.z, f1.w)));
      vbuf[0][r - a0 + 22][gx + 2] = m;
    }
  }
  __syncthreads();

  for (int t = 1; t <= 9; ++t) {
    int hh = 2 * (10 - t);
    int s = max(0, a0 - hh), e = min(64, a0 + 16 + hh);
    // phase A: quad sweeps; lane handles 4 px of row rb+roff, 4 channels
    for (int rb = s + 4 * slot; rb < e; rb += 16) {
      int r = rb + roff;
      if (r < e) {
        int lr = r - a0 + 22;
        const float4* qp =
            (const float4*)&q0b[(((size_t)r * 2 + half) * 64 + i4) * 4];
        float4 qv0 = qp[0], qv1 = qp[1], qv2 = qp[2], qv3 = qp[3];
        v2f aA[4], aB[4];
        aA[0] = (v2f){qv0.x, qv0.y}; aB[0] = (v2f){qv0.z, qv0.w};
        aA[1] = (v2f){qv1.x, qv1.y}; aB[1] = (v2f){qv1.z, qv1.w};
        aA[2] = (v2f){qv2.x, qv2.y}; aB[2] = (v2f){qv2.z, qv2.w};
        aA[3] = (v2f){qv3.x, qv3.y}; aB[3] = (v2f){qv3.z, qv3.w};
#pragma unroll
        for (int jj = 0; jj < 5; ++jj) {
          const float* row = &vbuf[cur][lr - 2 + jj][i4];
          float4 fa = *(const float4*)row;
          float4 fb = *(const float4*)(row + 4);
          float f[8] = {fa.x, fa.y, fa.z, fa.w, fb.x, fb.y, fb.z, fb.w};
#pragma unroll
          for (int kx = 0; kx < 5; ++kx) {
            int k = jj * 5 + kx;
            v2f w0 = wr0[k], w1 = wr1[k];
#pragma unroll
            for (int j = 0; j < 4; ++j) {
              v2f vv2 = (v2f){f[j + kx], f[j + kx]};
              aA[j] += w0 * vv2;
              aB[j] += w1 * vv2;
            }
          }
        }
        float m0 = fmaxf(fmaxf(aA[0].x, aA[0].y), fmaxf(aB[0].x, aB[0].y));
        float m1 = fmaxf(fmaxf(aA[1].x, aA[1].y), fmaxf(aB[1].x, aB[1].y));
        float m2 = fmaxf(fmaxf(aA[2].x, aA[2].y), fmaxf(aB[2].x, aB[2].y));
        float m3 = fmaxf(fmaxf(aA[3].x, aA[3].y), fmaxf(aB[3].x, aB[3].y));
        *(float4*)&tmp[lr - 4][half][i4] = make_float4(m0, m1, m2, m3);
      }
    }
    __syncthreads();
    // phase B: combine halves -> vbuf[cur^1]
    int n = e - s;
    for (int idx = tid; idx < n * 64; idx += 512) {
      int rr = idx >> 6, px = idx & 63;
      int lr2 = s - a0 + 22 + rr;
      vbuf[cur ^ 1][lr2][px + 2] =
          fmaxf(tmp[lr2 - 4][0][px], tmp[lr2 - 4][1][px]);
    }
    __syncthreads();
    cur ^= 1;
  }

  // final step t=10 + projection: rows [a0, a0+16), one quad sweep
  float fcp[4][4];
#pragma unroll
  for (int a = 0; a < 4; ++a)
#pragma unroll
    for (int cc = 0; cc < 4; ++cc) fcp[a][cc] = fc_w[a * 8 + 4 * half + cc];
  float* ptmp = (float*)tmp;  // [16][64][4] = 16 KB

  {
    int r = a0 + 4 * slot + roff;  // in [a0, a0+16)
    int lr = r - a0 + 22;
    const float4* qp =
        (const float4*)&q0b[(((size_t)r * 2 + half) * 64 + i4) * 4];
    float4 qv0 = qp[0], qv1 = qp[1], qv2 = qp[2], qv3 = qp[3];
    v2f aA[4], aB[4];
    aA[0] = (v2f){qv0.x, qv0.y}; aB[0] = (v2f){qv0.z, qv0.w};
    aA[1] = (v2f){qv1.x, qv1.y}; aB[1] = (v2f){qv1.z, qv1.w};
    aA[2] = (v2f){qv2.x, qv2.y}; aB[2] = (v2f){qv2.z, qv2.w};
    aA[3] = (v2f){qv3.x, qv3.y}; aB[3] = (v2f){qv3.z, qv3.w};
#pragma unroll
    for (int jj = 0; jj < 5; ++jj) {
      const float* row = &vbuf[cur][lr - 2 + jj][i4];
      float4 fa = *(const float4*)row;
      float4 fb = *(const float4*)(row + 4);
      float f[8] = {fa.x, fa.y, fa.z, fa.w, fb.x, fb.y, fb.z, fb.w};
#pragma unroll
      for (int kx = 0; kx < 5; ++kx) {
        int k = jj * 5 + kx;
        v2f w0 = wr0[k], w1 = wr1[k];
#pragma unroll
        for (int j = 0; j < 4; ++j) {
          v2f vv2 = (v2f){f[j + kx], f[j + kx]};
          aA[j] += w0 * vv2;
          aB[j] += w1 * vv2;
        }
      }
    }
    float4 pp[4];
#pragma unroll
    for (int j = 0; j < 4; ++j) {
      float q0v = aA[j].x, q1v = aA[j].y, q2v = aB[j].x, q3v = aB[j].y;
      pp[j].x = fcp[0][0] * q0v + fcp[0][1] * q1v + fcp[0][2] * q2v + fcp[0][3] * q3v;
      pp[j].y = fcp[1][0] * q0v + fcp[1][1] * q1v + fcp[1][2] * q2v + fcp[1][3] * q3v;
      pp[j].z = fcp[2][0] * q0v + fcp[2][1] * q1v + fcp[2][2] * q2v + fcp[2][3] * q3v;
      pp[j].w = fcp[3][0] * q0v + fcp[3][1] * q1v + fcp[3][2] * q2v + fcp[3][3] * q3v;
    }
    if (half == 1) {
#pragma unroll
      for (int j = 0; j < 4; ++j)
        *(float4*)&ptmp[(((r - a0) * 64) + i4 + j) * 4] = pp[j];
    }
    __syncthreads();
    if (half == 0) {
#pragma unroll
      for (int j = 0; j < 4; ++j) {
        float4 o = *(const float4*)&ptmp[(((r - a0) * 64) + i4 + j) * 4];
        o.x += pp[j].x; o.y += pp[j].y; o.z += pp[j].z; o.w += pp[j].w;
        *(float4*)&out[((size_t)((b * 64 + r) * 64 + i4 + j)) * 4] = o;
      }
    }
  }
}

extern "C" void kernel_launch(void* const* d_in, const int* in_sizes, int n_in,
                              void* d_out, int out_size, void* d_ws, size_t ws_size,
                              hipStream_t stream) {
  const int* maze = (const int*)d_in[0];
  const float* emb = (const float*)d_in[1];
  const float* encode_w = (const float*)d_in[2];
  const float* encode_b = (const float*)d_in[3];
  const float* r_w = (const float*)d_in[4];
  const float* q_w = (const float*)d_in[5];
  const float* w = (const float*)d_in[6];
  const float* fc_w = (const float*)d_in[7];
  float* out = (float*)d_out;

  float* q0g = (float*)d_ws;  // 64*64*2*64*4 floats = 8 MB

  rq_kernel<<<dim3(4, 64), 512, 0, stream>>>(maze, emb, encode_w, encode_b,
                                             r_w, q_w, q0g);
  vi_kernel<<<dim3(4, 64), 512, 0, stream>>>(q0g, w, fc_w, out);
}